// Round 2
// baseline (61.551 us; speedup 1.0000x reference)
//
#include <hip/hip_runtime.h>
#include <hip/hip_bf16.h>

#define NB 4
#define NH 16
#define SEQ 2048
#define EMB 512
#define DH 32
#define CHUNKQ 64
#define WIN 256

typedef __attribute__((ext_vector_type(8))) short short8;
typedef __attribute__((ext_vector_type(4))) float f32x4;

__device__ __forceinline__ ushort f2bf(float f) {
    union { float f; unsigned u; } c; c.f = f;
    unsigned u = c.u;
    unsigned r = u + 0x7FFFu + ((u >> 16) & 1u);   // round-to-nearest-even
    return (ushort)(r >> 16);
}

__device__ __forceinline__ short8 cvt8(float4 a, float4 b) {
    short8 r;
    r[0] = (short)f2bf(a.x); r[1] = (short)f2bf(a.y);
    r[2] = (short)f2bf(a.z); r[3] = (short)f2bf(a.w);
    r[4] = (short)f2bf(b.x); r[5] = (short)f2bf(b.y);
    r[6] = (short)f2bf(b.z); r[7] = (short)f2bf(b.w);
    return r;
}

// LDS: Vt [32][328] bf16 (V transposed, 20992 B) + Ps [64][72] bf16 (9216 B)
// total 30208 B -> 5 blocks/CU. Q and K fragments come straight from global
// (8 contiguous dims per lane = 32B), so no Q/K LDS and no staging barrier.

__global__ __launch_bounds__(256, 4)
void attn_chunk_kernel(const float* __restrict__ q, const float* __restrict__ k,
                       const float* __restrict__ v, float* __restrict__ out)
{
    constexpr int VSTR = 328;   // Vt row stride (bf16 elems); 16B-aligned rows, 2-way banks on read
    constexpr int PSTR = 72;    // Ps row stride; 16B-aligned rows, 2-way banks on read
    __shared__ __align__(16) ushort Vt[32 * VSTR];
    __shared__ __align__(16) ushort Ps[64 * PSTR];

    // XCD-aware swizzle: 2048 blocks, 8 XCDs -> contiguous 256-block chunk per XCD.
    // Consecutive cids share 256/320 of their key window -> per-XCD L2 locality.
    const unsigned bid = (blockIdx.x & 7) * 256 + (blockIdx.x >> 3);
    const int cid = bid & 31;          // chunk id
    const int h   = (bid >> 5) & 15;   // head
    const int b   = bid >> 9;          // batch
    const int q0  = cid * CHUNKQ;
    const int hi  = q0 + CHUNKQ;
    const int kstart = (hi - 320 > 0) ? (hi - 320) : 0;
    const int KT  = hi - kstart;       // 64/128/192/256/320 -- always a multiple of 64

    const int tid = threadIdx.x;

    // ---------------- stage V transposed (fp32 global -> bf16 LDS) ----------------
    // Issued first; its latency hides under QK^T + softmax (barrier is below).
    {
        const int e4 = (tid & 7) * 4;   // dim 0..28
        const int r0 = tid >> 3;        // key row 0..31
        for (int r = r0; r < KT; r += 32) {
            const float4 fv = *(const float4*)(v + ((size_t)(b * SEQ + kstart + r) * EMB + h * DH + e4));
            Vt[(e4 + 0) * VSTR + r] = f2bf(fv.x);
            Vt[(e4 + 1) * VSTR + r] = f2bf(fv.y);
            Vt[(e4 + 2) * VSTR + r] = f2bf(fv.z);
            Vt[(e4 + 3) * VSTR + r] = f2bf(fv.w);
        }
    }

    const int w   = tid >> 6;    // wave 0..3 owns query rows [16w, 16w+16)
    const int l   = tid & 63;
    const int l16 = l & 15;
    const int kg  = l >> 4;
    const int k0  = kg * 8;

    // ---------------- Q A-frag direct from global ----------------
    const float* qrow = q + ((size_t)(b * SEQ + q0 + 16 * w + l16) * EMB + h * DH + k0);
    const short8 aq = cvt8(*(const float4*)qrow, *(const float4*)(qrow + 4));

    // ---------------- QK^T: K B-frags direct from global ----------------
    const f32x4 zero = {0.f, 0.f, 0.f, 0.f};
    f32x4 s4[20];
    #pragma unroll
    for (int t = 0; t < 20; ++t) {
        if (t * 16 < KT) {
            const float* krow = k + ((size_t)(b * SEQ + kstart + t * 16 + l16) * EMB + h * DH + k0);
            const short8 bk = cvt8(*(const float4*)krow, *(const float4*)(krow + 4));
            s4[t] = __builtin_amdgcn_mfma_f32_16x16x32_bf16(aq, bk, zero, 0, 0, 0);
        }
    }

    // ---------------- softmax (full row in regs; D-layout row = 4*kg + r) ----------------
    const float scale = 0.17677669529663687f;  // 1/sqrt(32)
    float mrow[4] = {-1e30f, -1e30f, -1e30f, -1e30f};
    #pragma unroll
    for (int t = 0; t < 20; ++t) {
        if (t * 16 < KT) {
            const int kk = kstart + t * 16 + l16;
            #pragma unroll
            for (int r = 0; r < 4; ++r) {
                const int i = q0 + 16 * w + 4 * kg + r;
                float s = s4[t][r] * scale;
                s = (kk >= i - (WIN - 1)) ? s : -1e30f;   // allowed set is contiguous [i-255, hi)
                s4[t][r] = s;
                mrow[r] = fmaxf(mrow[r], s);
            }
        }
    }
    #pragma unroll
    for (int r = 0; r < 4; ++r) {
        #pragma unroll
        for (int m = 1; m <= 8; m <<= 1) mrow[r] = fmaxf(mrow[r], __shfl_xor(mrow[r], m));
    }
    float srow[4] = {0.f, 0.f, 0.f, 0.f};
    #pragma unroll
    for (int t = 0; t < 20; ++t) {
        if (t * 16 < KT) {
            #pragma unroll
            for (int r = 0; r < 4; ++r) {
                const float p = __expf(s4[t][r] - mrow[r]);
                s4[t][r] = p;
                srow[r] += p;
            }
        }
    }
    #pragma unroll
    for (int r = 0; r < 4; ++r) {
        #pragma unroll
        for (int m = 1; m <= 8; m <<= 1) srow[r] += __shfl_xor(srow[r], m);
    }

    __syncthreads();   // Vt ready (single barrier in the kernel)

    // ---------------- P->LDS (wave-private rows, no barriers) + PV, 64-key chunks ----------------
    f32x4 o0 = zero, o1 = zero;
    #pragma unroll
    for (int c = 0; c < 5; ++c) {
        if (c * 64 < KT) {        // KT % 64 == 0 -> active chunks are always full
            #pragma unroll
            for (int tt = 0; tt < 4; ++tt) {
                const int t = c * 4 + tt;
                ushort* dst = &Ps[(16 * w + 4 * kg) * PSTR + tt * 16 + l16];
                dst[0 * PSTR] = f2bf(s4[t][0]);
                dst[1 * PSTR] = f2bf(s4[t][1]);
                dst[2 * PSTR] = f2bf(s4[t][2]);
                dst[3 * PSTR] = f2bf(s4[t][3]);
            }
            #pragma unroll
            for (int sub = 0; sub < 2; ++sub) {
                const short8 pa  = *(const short8*)&Ps[(16 * w + l16) * PSTR + sub * 32 + k0];
                const short8 bv0 = *(const short8*)&Vt[l16 * VSTR + c * 64 + sub * 32 + k0];
                const short8 bv1 = *(const short8*)&Vt[(16 + l16) * VSTR + c * 64 + sub * 32 + k0];
                o0 = __builtin_amdgcn_mfma_f32_16x16x32_bf16(pa, bv0, o0, 0, 0, 0);
                o1 = __builtin_amdgcn_mfma_f32_16x16x32_bf16(pa, bv1, o1, 0, 0, 0);
            }
        }
    }

    // ---------------- epilogue ----------------
    #pragma unroll
    for (int r = 0; r < 4; ++r) {
        const int i = q0 + 16 * w + 4 * kg + r;
        const float inv = 1.0f / srow[r];
        float* dst = out + (size_t)(b * SEQ + i) * EMB + h * DH;
        dst[l16]      = o0[r] * inv;
        dst[16 + l16] = o1[r] * inv;
    }
}

extern "C" void kernel_launch(void* const* d_in, const int* in_sizes, int n_in,
                              void* d_out, int out_size, void* d_ws, size_t ws_size,
                              hipStream_t stream) {
    const float* q = (const float*)d_in[0];
    const float* k = (const float*)d_in[1];
    const float* v = (const float*)d_in[2];
    float* out = (float*)d_out;
    const int grid = NB * NH * (SEQ / CHUNKQ);   // 2048 blocks
    attn_chunk_kernel<<<grid, 256, 0, stream>>>(q, k, v, out);
}

// Round 3
// 31.947 us; speedup vs baseline: 1.9267x; 1.9267x over previous
//
#include <hip/hip_runtime.h>
#include <hip/hip_bf16.h>

#define NB 4
#define NH 16
#define SEQ 2048
#define EMB 512
#define DH 32
#define CHUNKQ 64
#define WIN 256

typedef __attribute__((ext_vector_type(8))) short short8;
typedef __attribute__((ext_vector_type(4))) float f32x4;

// packed f32x2 -> bf16x2 (RNE), 1 VALU op; no builtin on gfx950 (T12 recipe)
__device__ __forceinline__ unsigned cvt_pk_bf16(float lo, float hi) {
    unsigned r;
    asm("v_cvt_pk_bf16_f32 %0, %1, %2" : "=v"(r) : "v"(lo), "v"(hi));
    return r;
}

__device__ __forceinline__ ushort f2bf(float f) {
    union { float f; unsigned u; } c; c.f = f;
    unsigned u = c.u;
    unsigned r = u + 0x7FFFu + ((u >> 16) & 1u);   // round-to-nearest-even
    return (ushort)(r >> 16);
}

// LDS: Ks [320][40] bf16 (25600 B) + Vt [32][328] bf16 (20992 B)
//      + Pbuf 4 waves x [16][20] u32 (5120 B)  -> 51712 B -> 3 blocks/CU.
// Streaming flash structure, no running max (scores bounded, fp32 exp safe):
// swapped QK^T (A=K, B=Q) makes P key-major per lane -> row-sum in-lane,
// P transits a WAVE-PRIVATE Pbuf (no barriers; same-wave DS ordering --
// validated by round-2's identical pattern).

__global__ __launch_bounds__(256, 3)
void attn_chunk_kernel(const float* __restrict__ q, const float* __restrict__ k,
                       const float* __restrict__ v, float* __restrict__ out)
{
    constexpr int KSTR = 40;    // Ks row stride (bf16)
    constexpr int VSTR = 328;   // Vt row stride (bf16)
    constexpr int PSTR = 20;    // Pbuf row stride (u32)
    __shared__ __align__(16) ushort Ks[320 * KSTR];
    __shared__ __align__(16) ushort Vt[32 * VSTR];
    __shared__ __align__(16) unsigned Pbuf[4][16 * PSTR];

    // XCD-aware swizzle: 2048 blocks, 8 XCDs -> contiguous 256-block chunk/XCD
    const unsigned bid = (blockIdx.x & 7) * 256 + (blockIdx.x >> 3);
    const int cid = bid & 31;          // chunk id
    const int h   = (bid >> 5) & 15;   // head
    const int b   = bid >> 9;          // batch
    const int q0  = cid * CHUNKQ;
    const int hi  = q0 + CHUNKQ;
    const int kstart = (hi - 320 > 0) ? (hi - 320) : 0;
    const int KT  = hi - kstart;       // 64..320, multiple of 64

    const int tid = threadIdx.x;
    const int w   = tid >> 6;          // wave 0..3 owns queries [16w, 16w+16)
    const int l   = tid & 63;
    const int l16 = l & 15;
    const int kg  = l >> 4;            // 0..3
    const int k0  = kg * 8;            // dim slice for frags

    // ---- Q B-frag direct from global: Q[q=l16][dims 8kg..8kg+7] ----
    const float* qrow = q + ((size_t)(b * SEQ + q0 + 16 * w + l16) * EMB + h * DH + k0);
    const float4 qa = *(const float4*)qrow;
    const float4 qc = *(const float4*)(qrow + 4);
    union { short8 s; unsigned u[4]; } qb;
    qb.u[0] = cvt_pk_bf16(qa.x, qa.y);
    qb.u[1] = cvt_pk_bf16(qa.z, qa.w);
    qb.u[2] = cvt_pk_bf16(qc.x, qc.y);
    qb.u[3] = cvt_pk_bf16(qc.z, qc.w);

    // ---- cooperative staging: K rows -> Ks (bf16), V -> Vt (transposed) ----
    {
        const int e4 = (tid & 7) * 4;   // dim 0..28
        const int r0 = tid >> 3;        // key row 0..31
        for (int r = r0; r < KT; r += 32) {
            const size_t base = (size_t)(b * SEQ + kstart + r) * EMB + h * DH + e4;
            const float4 fk = *(const float4*)(k + base);
            const float4 fv = *(const float4*)(v + base);
            uint2 kw;
            kw.x = cvt_pk_bf16(fk.x, fk.y);
            kw.y = cvt_pk_bf16(fk.z, fk.w);
            *(uint2*)(Ks + r * KSTR + e4) = kw;     // 8B, aligned
            Vt[(e4 + 0) * VSTR + r] = f2bf(fv.x);   // transposed scatter
            Vt[(e4 + 1) * VSTR + r] = f2bf(fv.y);
            Vt[(e4 + 2) * VSTR + r] = f2bf(fv.z);
            Vt[(e4 + 3) * VSTR + r] = f2bf(fv.w);
        }
    }
    __syncthreads();   // the only barrier

    const float scale = 0.17677669529663687f;  // 1/sqrt(32)
    const int   iq    = q0 + 16 * w + l16;     // this lane's query (key-major domain)
    const int   lowk  = iq - (WIN - 1);        // allowed keys: [lowk, hi)
    unsigned* pw = &Pbuf[w][l16 * PSTR];

    const f32x4 zero = {0.f, 0.f, 0.f, 0.f};
    f32x4 o0 = zero, o1 = zero;
    float srow = 0.f;

    #pragma unroll
    for (int t = 0; t < 10; ++t) {
        if (t * 32 < KT) {
            // QK^T (swapped): A = K rows, B = Q. D[key=4kg+r][q=l16]
            const short8 ka = *(const short8*)(Ks + (32 * t + l16) * KSTR + k0);
            const short8 kb = *(const short8*)(Ks + (32 * t + 16 + l16) * KSTR + k0);
            f32x4 s_lo = __builtin_amdgcn_mfma_f32_16x16x32_bf16(ka, qb.s, zero, 0, 0, 0);
            f32x4 s_hi = __builtin_amdgcn_mfma_f32_16x16x32_bf16(kb, qb.s, zero, 0, 0, 0);

            // mask + exp (no max-sub: scores bounded, fp32-safe); sum in-lane
            const int kk = kstart + 32 * t + 4 * kg;
            float p[8];
            #pragma unroll
            for (int r = 0; r < 4; ++r) {
                p[r]     = (kk + r      >= lowk) ? __expf(s_lo[r] * scale) : 0.f;
                p[r + 4] = (kk + r + 16 >= lowk) ? __expf(s_hi[r] * scale) : 0.f;
            }
            srow += ((p[0] + p[1]) + (p[2] + p[3])) + ((p[4] + p[5]) + (p[6] + p[7]));

            // pack & transit through wave-private Pbuf to A-frag layout
            uint2 wlo, whi;
            wlo.x = cvt_pk_bf16(p[0], p[1]);  wlo.y = cvt_pk_bf16(p[2], p[3]);
            whi.x = cvt_pk_bf16(p[4], p[5]);  whi.y = cvt_pk_bf16(p[6], p[7]);
            *(uint2*)(pw + 2 * kg)     = wlo;   // keys 4kg..4kg+3
            *(uint2*)(pw + 8 + 2 * kg) = whi;   // keys 16+4kg..+3
            const short8 pa = *(const short8*)(pw + 4 * kg);  // P[q=l16][keys 8kg..8kg+7]

            // PV: B = Vt rows (dims), accumulate
            const short8 bv0 = *(const short8*)(Vt + l16 * VSTR + 32 * t + k0);
            const short8 bv1 = *(const short8*)(Vt + (16 + l16) * VSTR + 32 * t + k0);
            o0 = __builtin_amdgcn_mfma_f32_16x16x32_bf16(pa, bv0, o0, 0, 0, 0);
            o1 = __builtin_amdgcn_mfma_f32_16x16x32_bf16(pa, bv1, o1, 0, 0, 0);
        }
    }

    // ---- epilogue: reduce row-sum (keys partitioned over kg/halves), write ----
    srow += __shfl_xor(srow, 16);
    srow += __shfl_xor(srow, 32);   // srow(q=l16) valid in all kg groups
    #pragma unroll
    for (int r = 0; r < 4; ++r) {
        const float sq  = __shfl(srow, 4 * kg + r);     // srow for query 4kg+r
        const float inv = 1.0f / sq;
        float* dst = out + (size_t)(b * SEQ + q0 + 16 * w + 4 * kg + r) * EMB + h * DH;
        dst[l16]      = o0[r] * inv;
        dst[16 + l16] = o1[r] * inv;
    }
}

extern "C" void kernel_launch(void* const* d_in, const int* in_sizes, int n_in,
                              void* d_out, int out_size, void* d_ws, size_t ws_size,
                              hipStream_t stream) {
    const float* q = (const float*)d_in[0];
    const float* k = (const float*)d_in[1];
    const float* v = (const float*)d_in[2];
    float* out = (float*)d_out;
    const int grid = NB * NH * (SEQ / CHUNKQ);   // 2048 blocks
    attn_chunk_kernel<<<grid, 256, 0, stream>>>(q, k, v, out);
}

// Round 6
// 26.770 us; speedup vs baseline: 2.2992x; 1.1934x over previous
//
#include <hip/hip_runtime.h>
#include <hip/hip_bf16.h>

#define NB 4
#define NH 16
#define SEQ 2048
#define EMB 512
#define DH 32
#define CHUNKQ 64
#define WIN 256

typedef __attribute__((ext_vector_type(8))) short short8;
typedef __attribute__((ext_vector_type(4))) float f32x4;

// packed f32x2 -> bf16x2 (RNE); HW-validated round 3
__device__ __forceinline__ unsigned cvt_pk_bf16(float lo, float hi) {
    unsigned r;
    asm("v_cvt_pk_bf16_f32 %0, %1, %2" : "=v"(r) : "v"(lo), "v"(hi));
    return r;
}

__device__ __forceinline__ ushort f2bf(float f) {
    union { float f; unsigned u; } c; c.f = f;
    unsigned u = c.u;
    unsigned r = u + 0x7FFFu + ((u >> 16) & 1u);   // round-to-nearest-even
    return (ushort)(r >> 16);
}

// === r3 (green, 31.9us) + ONE delta: batched unconditional staging ===
// LDS: Ks [320][40] bf16 (25600 B) + Vt [32][328] bf16 (20992 B)
//      + Pbuf 4 waves x [16][20] u32 (5120 B)  -> 51712 B -> 3 blocks/CU.
// Streaming flash structure, no running max (scores bounded, fp32 exp safe);
// swapped QK^T (A=K, B=Q) -> P key-major per lane -> row-sum in-lane;
// P transits a WAVE-PRIVATE Pbuf (no barriers, same-wave DS ordering).
// Staging delta: all 20 global float4 loads issued unconditionally up front
// (rows kstart+r0+32it <= hi-1 <= 2047 always in-bounds; extra columns are
// written to LDS but never read -- main loop keeps its t*32<KT guard).

__global__ __launch_bounds__(256, 3)
void attn_chunk_kernel(const float* __restrict__ q, const float* __restrict__ k,
                       const float* __restrict__ v, float* __restrict__ out)
{
    constexpr int KSTR = 40;    // Ks row stride (bf16)
    constexpr int VSTR = 328;   // Vt row stride (bf16)
    constexpr int PSTR = 20;    // Pbuf row stride (u32)
    __shared__ __align__(16) ushort Ks[320 * KSTR];
    __shared__ __align__(16) ushort Vt[32 * VSTR];
    __shared__ __align__(16) unsigned Pbuf[4][16 * PSTR];

    // XCD-aware swizzle: 2048 blocks, 8 XCDs -> contiguous 256-block chunk/XCD
    const unsigned bid = (blockIdx.x & 7) * 256 + (blockIdx.x >> 3);
    const int cid = bid & 31;          // chunk id
    const int h   = (bid >> 5) & 15;   // head
    const int b   = bid >> 9;          // batch
    const int q0  = cid * CHUNKQ;
    const int hi  = q0 + CHUNKQ;
    const int kstart = (hi - 320 > 0) ? (hi - 320) : 0;
    const int KT  = hi - kstart;       // 64..320, multiple of 64

    const int tid = threadIdx.x;
    const int e4  = (tid & 7) * 4;     // dim 0,4,..,28
    const int r0  = tid >> 3;          // key row 0..31

    // ---- staging loads: ALL 20 float4 issued first, unconditional ----
    float4 fk[10], fv[10];
    #pragma unroll
    for (int it = 0; it < 10; ++it) {
        const size_t base = (size_t)(b * SEQ + kstart + r0 + it * 32) * EMB + h * DH + e4;
        fk[it] = *(const float4*)(k + base);
        fv[it] = *(const float4*)(v + base);
    }

    const int w   = tid >> 6;          // wave 0..3 owns queries [16w, 16w+16)
    const int l   = tid & 63;
    const int l16 = l & 15;
    const int kg  = l >> 4;            // 0..3
    const int k0  = kg * 8;            // dim slice for frags

    // ---- Q B-frag direct from global (overlaps the staging-load latency) ----
    const float* qrow = q + ((size_t)(b * SEQ + q0 + 16 * w + l16) * EMB + h * DH + k0);
    const float4 qa = *(const float4*)qrow;
    const float4 qc = *(const float4*)(qrow + 4);
    union { short8 s; unsigned u[4]; } qb;
    qb.u[0] = cvt_pk_bf16(qa.x, qa.y);
    qb.u[1] = cvt_pk_bf16(qa.z, qa.w);
    qb.u[2] = cvt_pk_bf16(qc.x, qc.y);
    qb.u[3] = cvt_pk_bf16(qc.z, qc.w);

    // ---- staging converts + LDS writes (unconditional) ----
    #pragma unroll
    for (int it = 0; it < 10; ++it) {
        uint2 kw;
        kw.x = cvt_pk_bf16(fk[it].x, fk[it].y);
        kw.y = cvt_pk_bf16(fk[it].z, fk[it].w);
        *(uint2*)(Ks + (r0 + it * 32) * KSTR + e4) = kw;   // 8B aligned
        Vt[(e4 + 0) * VSTR + r0 + it * 32] = f2bf(fv[it].x);   // transposed scatter
        Vt[(e4 + 1) * VSTR + r0 + it * 32] = f2bf(fv[it].y);
        Vt[(e4 + 2) * VSTR + r0 + it * 32] = f2bf(fv[it].z);
        Vt[(e4 + 3) * VSTR + r0 + it * 32] = f2bf(fv[it].w);
    }
    __syncthreads();   // the only barrier

    const float scale = 0.17677669529663687f;  // 1/sqrt(32)
    const int   iq    = q0 + 16 * w + l16;     // this lane's query (key-major domain)
    const int   lowk  = iq - (WIN - 1);        // allowed keys: [lowk, hi)
    unsigned* pw = &Pbuf[w][l16 * PSTR];

    const f32x4 zero = {0.f, 0.f, 0.f, 0.f};
    f32x4 o0 = zero, o1 = zero;
    float srow = 0.f;

    #pragma unroll
    for (int t = 0; t < 10; ++t) {
        if (t * 32 < KT) {
            // QK^T (swapped): A = K rows, B = Q. D[key=4kg+r][q=l16]
            const short8 ka = *(const short8*)(Ks + (32 * t + l16) * KSTR + k0);
            const short8 kb = *(const short8*)(Ks + (32 * t + 16 + l16) * KSTR + k0);
            f32x4 s_lo = __builtin_amdgcn_mfma_f32_16x16x32_bf16(ka, qb.s, zero, 0, 0, 0);
            f32x4 s_hi = __builtin_amdgcn_mfma_f32_16x16x32_bf16(kb, qb.s, zero, 0, 0, 0);

            // mask + exp (no max-sub: scores bounded, fp32-safe); sum in-lane
            const int kk = kstart + 32 * t + 4 * kg;
            float p[8];
            #pragma unroll
            for (int r = 0; r < 4; ++r) {
                p[r]     = (kk + r      >= lowk) ? __expf(s_lo[r] * scale) : 0.f;
                p[r + 4] = (kk + r + 16 >= lowk) ? __expf(s_hi[r] * scale) : 0.f;
            }
            srow += ((p[0] + p[1]) + (p[2] + p[3])) + ((p[4] + p[5]) + (p[6] + p[7]));

            // pack & transit through wave-private Pbuf to A-frag layout
            uint2 wlo, whi;
            wlo.x = cvt_pk_bf16(p[0], p[1]);  wlo.y = cvt_pk_bf16(p[2], p[3]);
            whi.x = cvt_pk_bf16(p[4], p[5]);  whi.y = cvt_pk_bf16(p[6], p[7]);
            *(uint2*)(pw + 2 * kg)     = wlo;   // keys 4kg..4kg+3
            *(uint2*)(pw + 8 + 2 * kg) = whi;   // keys 16+4kg..+3
            const short8 pa = *(const short8*)(pw + 4 * kg);  // P[q=l16][keys 8kg..8kg+7]

            // PV: B = Vt rows (dims), accumulate
            const short8 bv0 = *(const short8*)(Vt + l16 * VSTR + 32 * t + k0);
            const short8 bv1 = *(const short8*)(Vt + (16 + l16) * VSTR + 32 * t + k0);
            o0 = __builtin_amdgcn_mfma_f32_16x16x32_bf16(pa, bv0, o0, 0, 0, 0);
            o1 = __builtin_amdgcn_mfma_f32_16x16x32_bf16(pa, bv1, o1, 0, 0, 0);
        }
    }

    // ---- epilogue: reduce row-sum (keys partitioned over kg/halves), write ----
    srow += __shfl_xor(srow, 16);
    srow += __shfl_xor(srow, 32);   // srow(q=l16) valid in all kg groups
    #pragma unroll
    for (int r = 0; r < 4; ++r) {
        const float sq  = __shfl(srow, 4 * kg + r);     // srow for query 4kg+r
        const float inv = 1.0f / sq;
        float* dst = out + (size_t)(b * SEQ + q0 + 16 * w + 4 * kg + r) * EMB + h * DH;
        dst[l16]      = o0[r] * inv;
        dst[16 + l16] = o1[r] * inv;
    }
}

extern "C" void kernel_launch(void* const* d_in, const int* in_sizes, int n_in,
                              void* d_out, int out_size, void* d_ws, size_t ws_size,
                              hipStream_t stream) {
    const float* q = (const float*)d_in[0];
    const float* k = (const float*)d_in[1];
    const float* v = (const float*)d_in[2];
    float* out = (float*)d_out;
    const int grid = NB * NH * (SEQ / CHUNKQ);   // 2048 blocks
    attn_chunk_kernel<<<grid, 256, 0, stream>>>(q, k, v, out);
}

// Round 8
// 26.439 us; speedup vs baseline: 2.3281x; 1.0126x over previous
//
#include <hip/hip_runtime.h>
#include <hip/hip_bf16.h>

#define NB 4
#define NH 16
#define SEQ 2048
#define EMB 512
#define DH 32
#define CHUNKQ 64
#define WIN 256

typedef __attribute__((ext_vector_type(8))) short short8;
typedef __attribute__((ext_vector_type(4))) float f32x4;

// packed f32x2 -> bf16x2 (RNE); HW-validated rounds 3/6
__device__ __forceinline__ unsigned cvt_pk_bf16(float lo, float hi) {
    unsigned r;
    asm("v_cvt_pk_bf16_f32 %0, %1, %2" : "=v"(r) : "v"(lo), "v"(hi));
    return r;
}

// === r6 (green, 26.8us) + ONE delta: conflict-reduced V staging ===
// LDS: Ks [320][40] bf16 (25600 B) + Vt [32][328] bf16 (20992 B)
//      + Pbuf 4 waves x [16][20] u32 (5120 B)  -> 51712 B -> 3 blocks/CU.
//
// V staging remapped: thread (d2=(tid&15)*2, kp=tid>>4) loads float2 pairs of
// keys 32it+2kp, +1 (coalesced 128B per 16-lane group) and writes TWO
// ds_write_b32 (key-pairs packed via cvt_pk). Banks (4*dim + kp) mod 32 =
// 16 banks/wave = 4-way on b32, vs old transposed-scatter's 4x ds_write_b16
// at 8 banks/wave (8-way). Vt contents byte-identical; main loop untouched.
//
// Rest identical to r6: streaming flash, no running max (scores bounded);
// swapped QK^T (A=K, B=Q) -> P key-major; P transits wave-private Pbuf.

__global__ __launch_bounds__(256, 3)
void attn_chunk_kernel(const float* __restrict__ q, const float* __restrict__ k,
                       const float* __restrict__ v, float* __restrict__ out)
{
    constexpr int KSTR = 40;    // Ks row stride (bf16)
    constexpr int VSTR = 328;   // Vt row stride (bf16)
    constexpr int PSTR = 20;    // Pbuf row stride (u32)
    __shared__ __align__(16) ushort Ks[320 * KSTR];
    __shared__ __align__(16) ushort Vt[32 * VSTR];
    __shared__ __align__(16) unsigned Pbuf[4][16 * PSTR];

    // XCD-aware swizzle: 2048 blocks, 8 XCDs -> contiguous 256-block chunk/XCD
    const unsigned bid = (blockIdx.x & 7) * 256 + (blockIdx.x >> 3);
    const int cid = bid & 31;          // chunk id
    const int h   = (bid >> 5) & 15;   // head
    const int b   = bid >> 9;          // batch
    const int q0  = cid * CHUNKQ;
    const int hi  = q0 + CHUNKQ;
    const int kstart = (hi - 320 > 0) ? (hi - 320) : 0;
    const int KT  = hi - kstart;       // 64..320, multiple of 64

    const int tid = threadIdx.x;
    const int e4  = (tid & 7) * 4;     // K-staging dim 0,4,..,28
    const int r0  = tid >> 3;          // K-staging key row 0..31
    const int d2  = (tid & 15) * 2;    // V-staging dim pair base 0,2,..,30
    const int kp  = tid >> 4;          // V-staging key-pair 0..15

    // ---- staging loads: ALL issued first, unconditional (always in-bounds:
    //      kstart + row <= hi-1 <= 2047; extra cols written but never read) ----
    float4 fk[10];
    float2 va[10], vb[10];
    #pragma unroll
    for (int it = 0; it < 10; ++it) {
        const size_t kbase = (size_t)(b * SEQ + kstart + r0 + it * 32) * EMB + h * DH + e4;
        fk[it] = *(const float4*)(k + kbase);
        const size_t vbase = (size_t)(b * SEQ + kstart + 32 * it + 2 * kp) * EMB + h * DH + d2;
        va[it] = *(const float2*)(v + vbase);          // key 32it+2kp, dims d2,d2+1
        vb[it] = *(const float2*)(v + vbase + EMB);    // key 32it+2kp+1
    }

    const int w   = tid >> 6;          // wave 0..3 owns queries [16w, 16w+16)
    const int l   = tid & 63;
    const int l16 = l & 15;
    const int kg  = l >> 4;            // 0..3
    const int k0  = kg * 8;            // dim slice for frags

    // ---- Q B-frag direct from global (overlaps the staging-load latency) ----
    const float* qrow = q + ((size_t)(b * SEQ + q0 + 16 * w + l16) * EMB + h * DH + k0);
    const float4 qa = *(const float4*)qrow;
    const float4 qc = *(const float4*)(qrow + 4);
    union { short8 s; unsigned u[4]; } qb;
    qb.u[0] = cvt_pk_bf16(qa.x, qa.y);
    qb.u[1] = cvt_pk_bf16(qa.z, qa.w);
    qb.u[2] = cvt_pk_bf16(qc.x, qc.y);
    qb.u[3] = cvt_pk_bf16(qc.z, qc.w);

    // ---- staging converts + LDS writes (unconditional) ----
    #pragma unroll
    for (int it = 0; it < 10; ++it) {
        uint2 kw;
        kw.x = cvt_pk_bf16(fk[it].x, fk[it].y);
        kw.y = cvt_pk_bf16(fk[it].z, fk[it].w);
        *(uint2*)(Ks + (r0 + it * 32) * KSTR + e4) = kw;   // 8B aligned, conflict-free
        // V: key-pair packed b32 writes, 4-way banks (was 8-way b16 scatter)
        *(unsigned*)(Vt + (d2 + 0) * VSTR + 32 * it + 2 * kp) = cvt_pk_bf16(va[it].x, vb[it].x);
        *(unsigned*)(Vt + (d2 + 1) * VSTR + 32 * it + 2 * kp) = cvt_pk_bf16(va[it].y, vb[it].y);
    }
    __syncthreads();   // the only barrier

    const float scale = 0.17677669529663687f;  // 1/sqrt(32)
    const int   iq    = q0 + 16 * w + l16;     // this lane's query (key-major domain)
    const int   lowk  = iq - (WIN - 1);        // allowed keys: [lowk, hi)
    unsigned* pw = &Pbuf[w][l16 * PSTR];

    const f32x4 zero = {0.f, 0.f, 0.f, 0.f};
    f32x4 o0 = zero, o1 = zero;
    float srow = 0.f;

    #pragma unroll
    for (int t = 0; t < 10; ++t) {
        if (t * 32 < KT) {
            // QK^T (swapped): A = K rows, B = Q. D[key=4kg+r][q=l16]
            const short8 ka = *(const short8*)(Ks + (32 * t + l16) * KSTR + k0);
            const short8 kb = *(const short8*)(Ks + (32 * t + 16 + l16) * KSTR + k0);
            f32x4 s_lo = __builtin_amdgcn_mfma_f32_16x16x32_bf16(ka, qb.s, zero, 0, 0, 0);
            f32x4 s_hi = __builtin_amdgcn_mfma_f32_16x16x32_bf16(kb, qb.s, zero, 0, 0, 0);

            // mask + exp (no max-sub: scores bounded, fp32-safe); sum in-lane
            const int kk = kstart + 32 * t + 4 * kg;
            float p[8];
            #pragma unroll
            for (int r = 0; r < 4; ++r) {
                p[r]     = (kk + r      >= lowk) ? __expf(s_lo[r] * scale) : 0.f;
                p[r + 4] = (kk + r + 16 >= lowk) ? __expf(s_hi[r] * scale) : 0.f;
            }
            srow += ((p[0] + p[1]) + (p[2] + p[3])) + ((p[4] + p[5]) + (p[6] + p[7]));

            // pack & transit through wave-private Pbuf to A-frag layout
            uint2 wlo, whi;
            wlo.x = cvt_pk_bf16(p[0], p[1]);  wlo.y = cvt_pk_bf16(p[2], p[3]);
            whi.x = cvt_pk_bf16(p[4], p[5]);  whi.y = cvt_pk_bf16(p[6], p[7]);
            *(uint2*)(pw + 2 * kg)     = wlo;   // keys 4kg..4kg+3
            *(uint2*)(pw + 8 + 2 * kg) = whi;   // keys 16+4kg..+3
            const short8 pa = *(const short8*)(pw + 4 * kg);  // P[q=l16][keys 8kg..8kg+7]

            // PV: B = Vt rows (dims), accumulate
            const short8 bv0 = *(const short8*)(Vt + l16 * VSTR + 32 * t + k0);
            const short8 bv1 = *(const short8*)(Vt + (16 + l16) * VSTR + 32 * t + k0);
            o0 = __builtin_amdgcn_mfma_f32_16x16x32_bf16(pa, bv0, o0, 0, 0, 0);
            o1 = __builtin_amdgcn_mfma_f32_16x16x32_bf16(pa, bv1, o1, 0, 0, 0);
        }
    }

    // ---- epilogue: reduce row-sum (keys partitioned over kg/halves), write ----
    srow += __shfl_xor(srow, 16);
    srow += __shfl_xor(srow, 32);   // srow(q=l16) valid in all kg groups
    #pragma unroll
    for (int r = 0; r < 4; ++r) {
        const float sq  = __shfl(srow, 4 * kg + r);     // srow for query 4kg+r
        const float inv = 1.0f / sq;
        float* dst = out + (size_t)(b * SEQ + q0 + 16 * w + 4 * kg + r) * EMB + h * DH;
        dst[l16]      = o0[r] * inv;
        dst[16 + l16] = o1[r] * inv;
    }
}

extern "C" void kernel_launch(void* const* d_in, const int* in_sizes, int n_in,
                              void* d_out, int out_size, void* d_ws, size_t ws_size,
                              hipStream_t stream) {
    const float* q = (const float*)d_in[0];
    const float* k = (const float*)d_in[1];
    const float* v = (const float*)d_in[2];
    float* out = (float*)d_out;
    const int grid = NB * NH * (SEQ / CHUNKQ);   // 2048 blocks
    attn_chunk_kernel<<<grid, 256, 0, stream>>>(q, k, v, out);
}